// Round 10
// baseline (364.825 us; speedup 1.0000x reference)
//
#include <hip/hip_runtime.h>
#include <hip/hip_bf16.h>
#include <math.h>

#define NN 25000
#define NE 250000
#define DD 64
#define HH 4
#define NGROUP (NE / 16)   // 15625 16-edge groups
#define NGX ((NN + 15) / 16)  // 1563 16-node groups for k_xw
#define NB 98              // ceil(NN/256) scan blocks

typedef __attribute__((ext_vector_type(8))) short bf16x8;
typedef __attribute__((ext_vector_type(4))) float f32x4;

#define WB_LD 72    // 64 + 8 pad (shorts) -> 144B row stride

__device__ __forceinline__ float softplus_f(float x) {
    return fmaxf(x, 0.0f) + __logf(1.0f + __expf(-fabsf(x)));
}

__device__ __forceinline__ unsigned short f2bf(float f) {
    __hip_bfloat16 h = __float2bfloat16(f);
    unsigned short u;
    __builtin_memcpy(&u, &h, 2);
    return u;
}

__device__ __forceinline__ float bf2f(unsigned short u) {
    return __uint_as_float(((unsigned int)u) << 16);
}

// Load 8 consecutive floats, split each into bf16 hi + bf16 lo (compensated).
__device__ __forceinline__ void load8(const float* p, bf16x8& hi, bf16x8& lo) {
    float4 a = *(const float4*)p;
    float4 b = *(const float4*)(p + 4);
    float v[8] = {a.x, a.y, a.z, a.w, b.x, b.y, b.z, b.w};
#pragma unroll
    for (int i = 0; i < 8; ++i) {
        unsigned short h = f2bf(v[i]);
        hi[i] = (short)h;
        lo[i] = (short)f2bf(v[i] - bf2f(h));
    }
}

// ===== k_xw: xW = x @ W_top (rows 0..63), fp32 out, computed ONCE per node =====
// Same compensated bf16 math as the old per-edge x-GEMV -> numerics unchanged.
__global__ __launch_bounds__(512, 4)
void k_xw(const float* __restrict__ x, const float* __restrict__ W,
          float* __restrict__ xw)
{
    __shared__ unsigned short Wsh[256 * WB_LD];  // W_top^T bf16 [n][k]
    const int tid = threadIdx.x;
    const int lane = tid & 63;
    const int q = lane >> 4;
    const int r = lane & 15;

    for (int idx = tid; idx < 16384; idx += 512) {
        int k = idx >> 8, n = idx & 255;
        Wsh[n * WB_LD + k] = f2bf(W[k * 256 + n]);
    }
    __syncthreads();

    const int gw = blockIdx.x * 8 + (tid >> 6);
    const int nw = gridDim.x * 8;

    for (int g = gw; g < NGX; g += nw) {
        const int node = g * 16 + r;
        const int nd = (node < NN) ? node : (NN - 1);
        const float* xp = x + (size_t)nd * DD;
        bf16x8 Ahi[2], Alo[2];
        load8(xp + q * 8,      Ahi[0], Alo[0]);
        load8(xp + 32 + q * 8, Ahi[1], Alo[1]);

#pragma unroll
        for (int nt = 0; nt < 4; ++nt) {
            f32x4 acc[4];
#pragma unroll
            for (int h = 0; h < 4; ++h) acc[h] = (f32x4){0.f, 0.f, 0.f, 0.f};
#pragma unroll
            for (int h = 0; h < 4; ++h) {
                const unsigned short* bp = &Wsh[((nt + 4 * h) * 16 + r) * WB_LD + q * 8];
#pragma unroll
                for (int kt = 0; kt < 2; ++kt) {
                    bf16x8 bf = *(const bf16x8*)(bp + kt * 32);
                    acc[h] = __builtin_amdgcn_mfma_f32_16x16x32_bf16(Ahi[kt], bf, acc[h], 0, 0, 0);
                    acc[h] = __builtin_amdgcn_mfma_f32_16x16x32_bf16(Alo[kt], bf, acc[h], 0, 0, 0);
                }
            }
            // C row (node-local) = q*4+reg, col = nt*16+r + 64h
#pragma unroll
            for (int reg = 0; reg < 4; ++reg) {
                const int row = g * 16 + q * 4 + reg;
                if (row < NN) {
#pragma unroll
                    for (int h = 0; h < 4; ++h)
                        xw[(size_t)row * 256 + 64 * h + nt * 16 + r] = acc[h][reg];
                }
            }
        }
    }
}

// ===== k_edge v2: only ea@W_bot on MFMA (shared i/j); x-parts read from xW =====
// xW (25.6MB) is L3-resident -> the ~500MB of re-reads are Infinity-Cache hits.
// Reads in C-layout: for fixed (reg,h), lanes r=0..15 hit 16 consecutive floats.
// Spill tripwire (r3/r7): if FETCH/WRITE balloon vs ~110/235MB, revert.
__global__ __launch_bounds__(512, 4)
void k_edge(const float* __restrict__ ea, const float* __restrict__ W,
            const float* __restrict__ att,
            const float* __restrict__ bn_g, const float* __restrict__ bn_b,
            const float* __restrict__ bn_m, const float* __restrict__ bn_v,
            const int* __restrict__ eidx, const int* __restrict__ perm,
            const float* __restrict__ xw,
            unsigned short* __restrict__ outj,
            float* __restrict__ expa, float* __restrict__ denom)
{
    __shared__ unsigned short Wsh[256 * WB_LD];  // W_bot^T bf16 [n][k-64]
    __shared__ float attI[256], attJ[256];

    const int tid = threadIdx.x;
    const int lane = tid & 63;
    const int q = lane >> 4;
    const int r = lane & 15;

    for (int idx = tid; idx < 16384; idx += 512) {
        int k = idx >> 8, n = idx & 255;
        Wsh[n * WB_LD + k] = f2bf(W[(64 + k) * 256 + n]);
    }
    if (tid < 256) {
        int c = tid;
        attI[c] = att[(c >> 6) * 128 + (c & 63)];
        attJ[c] = att[(c >> 6) * 128 + 64 + (c & 63)];
    }
    float bnsc[HH], bnsh[HH];
#pragma unroll
    for (int t = 0; t < HH; ++t) {
        float inv = rsqrtf(bn_v[t] + 1e-5f);
        bnsc[t] = bn_g[t] * inv;
        bnsh[t] = bn_b[t] - bn_m[t] * bn_g[t] * inv;
    }
    __syncthreads();

    const int gw = blockIdx.x * 8 + (tid >> 6);
    const int nw = gridDim.x * 8;

    for (int g = gw; g < NGROUP; g += nw) {
        const int e0 = g * 16;                 // sorted-position base
        const int pe = perm[e0 + r];           // edge id at this position
        const int ei = eidx[pe];               // target node (sorted-clustered)
        const int ej = eidx[NE + pe];
        const float* ev = ea + (size_t)pe * DD;

        bf16x8 Ahi[2], Alo[2];
        load8(ev + q * 8,      Ahi[0], Alo[0]);
        load8(ev + 32 + q * 8, Ahi[1], Alo[1]);

        // node ids + xW row pointers for this quad's 4 edges
        int ii[4];
        const float* xwi[4];
        const float* xwj[4];
#pragma unroll
        for (int reg = 0; reg < 4; ++reg) {
            ii[reg] = __shfl(ei, q * 4 + reg, 16);
            const int jjr = __shfl(ej, q * 4 + reg, 16);
            xwi[reg] = xw + (size_t)ii[reg] * 256;
            xwj[reg] = xw + (size_t)jjr * 256;
        }

        float lg[4][4];  // [reg][head]
#pragma unroll
        for (int a = 0; a < 4; ++a)
#pragma unroll
            for (int b = 0; b < 4; ++b) lg[a][b] = 0.f;

#pragma unroll
        for (int nt = 0; nt < 4; ++nt) {
            f32x4 aeC[4];
#pragma unroll
            for (int h = 0; h < 4; ++h) aeC[h] = (f32x4){0.f, 0.f, 0.f, 0.f};
#pragma unroll
            for (int h = 0; h < 4; ++h) {
                const unsigned short* bp = &Wsh[((nt + 4 * h) * 16 + r) * WB_LD + q * 8];
#pragma unroll
                for (int kt = 0; kt < 2; ++kt) {
                    bf16x8 bf = *(const bf16x8*)(bp + kt * 32);
                    aeC[h] = __builtin_amdgcn_mfma_f32_16x16x32_bf16(Ahi[kt], bf, aeC[h], 0, 0, 0);
                    aeC[h] = __builtin_amdgcn_mfma_f32_16x16x32_bf16(Alo[kt], bf, aeC[h], 0, 0, 0);
                }
            }
            const int cbase = nt * 16 + r;
#pragma unroll
            for (int reg = 0; reg < 4; ++reg) {
                ushort4 pk;
                unsigned short* pkp = (unsigned short*)&pk;
#pragma unroll
                for (int h = 0; h < 4; ++h) {
                    const int c = cbase + 64 * h;
                    float ci = xwi[reg][c] + aeC[h][reg];
                    float cj = xwj[reg][c] + aeC[h][reg];
                    float spi = softplus_f(ci);
                    float spj = softplus_f(cj);
                    lg[reg][h] += spi * attI[c] + spj * attJ[c];
                    pkp[h] = f2bf(spj);
                }
                const unsigned p = (unsigned)(e0 + q * 4 + reg);  // sorted position
                *(ushort4*)&outj[p * 256 + cbase * 4] = pk;
            }
        }

        // ---- logit reduce + BN + exp + denom ----
#pragma unroll
        for (int off = 1; off < 16; off <<= 1) {
#pragma unroll
            for (int a = 0; a < 4; ++a)
#pragma unroll
                for (int b = 0; b < 4; ++b)
                    lg[a][b] += __shfl_xor(lg[a][b], off, 64);
        }
        float exv[4][4];
#pragma unroll
        for (int reg = 0; reg < 4; ++reg)
#pragma unroll
            for (int h = 0; h < 4; ++h)
                exv[reg][h] = __expf(softplus_f(fmaf(lg[reg][h], bnsc[h], bnsh[h])));

        if (r < 4) {  // lane r handles head r for its quad's 4 edges
#pragma unroll
            for (int reg = 0; reg < 4; ++reg) {
                const int p = e0 + q * 4 + reg;      // sorted position
                expa[p * 4 + r] = exv[reg][r];
                atomicAdd(&denom[ii[reg] * 4 + r], exv[reg][r]);
            }
        }
    }
}

// ===== counting sort of edges by target node (multi-CU scan) =====
__global__ __launch_bounds__(256)
void k_hist(const int* __restrict__ eidx, int* __restrict__ cnt) {
    const int e = blockIdx.x * 256 + threadIdx.x;
    if (e < NE) atomicAdd(&cnt[eidx[e]], 1);
}

__global__ __launch_bounds__(256)
void k_scanA(const int* __restrict__ cnt, int* __restrict__ offs,
             int* __restrict__ bsum) {
    __shared__ int s[256];
    const int tid = threadIdx.x;
    const int i = blockIdx.x * 256 + tid;
    int v = (i < NN) ? cnt[i] : 0;
    s[tid] = v;
    __syncthreads();
#pragma unroll
    for (int off = 1; off < 256; off <<= 1) {
        int t = (tid >= off) ? s[tid - off] : 0;
        __syncthreads();
        s[tid] += t;
        __syncthreads();
    }
    if (i < NN) offs[i] = s[tid] - v;
    if (tid == 255) bsum[blockIdx.x] = s[255];
}

__global__ __launch_bounds__(128)
void k_scanB(const int* __restrict__ bsum, int* __restrict__ bbase) {
    __shared__ int s[128];
    const int tid = threadIdx.x;
    int v = (tid < NB) ? bsum[tid] : 0;
    s[tid] = v;
    __syncthreads();
#pragma unroll
    for (int off = 1; off < 128; off <<= 1) {
        int t = (tid >= off) ? s[tid - off] : 0;
        __syncthreads();
        s[tid] += t;
        __syncthreads();
    }
    if (tid < NB) bbase[tid] = s[tid] - v;
}

__global__ __launch_bounds__(256)
void k_scanC(int* __restrict__ offs, const int* __restrict__ bbase,
             int* __restrict__ cursor) {
    const int i = blockIdx.x * 256 + threadIdx.x;
    if (i < NN) {
        const int o = offs[i] + bbase[blockIdx.x];
        offs[i] = o;
        cursor[i] = o;
    }
    if (i == 0) offs[NN] = NE;
}

__global__ __launch_bounds__(256)
void k_place(const int* __restrict__ eidx, int* __restrict__ cursor,
             int* __restrict__ perm) {
    const int e = blockIdx.x * 256 + threadIdx.x;
    if (e < NE) {
        const int pos = atomicAdd(&cursor[eidx[e]], 1);
        perm[pos] = e;
    }
}

// One wave per node, lane = dim d. outj/expa stored in sorted position order
// -> pure sequential stream (no indirection, no atomics).
__global__ __launch_bounds__(256)
void k_aggr(const int* __restrict__ offs,
            const unsigned short* __restrict__ outj,
            const float* __restrict__ expa,
            const float* __restrict__ denom,
            const float* __restrict__ bias,
            float* __restrict__ out)
{
    const int n = blockIdx.x * 4 + (threadIdx.x >> 6);
    if (n >= NN) return;
    const int lane = threadIdx.x & 63;
    const int k0 = offs[n], k1 = offs[n + 1];
    const float4 dv = *(const float4*)&denom[n * 4];
    float num0 = 0.f, num1 = 0.f, num2 = 0.f, num3 = 0.f;
    for (int k = k0; k < k1; ++k) {
        const float4 ex = *(const float4*)&expa[k * 4];
        const ushort4 v = *(const ushort4*)&outj[((unsigned)k << 8) | (lane << 2)];
        num0 += ex.x * bf2f(v.x);
        num1 += ex.y * bf2f(v.y);
        num2 += ex.z * bf2f(v.z);
        num3 += ex.w * bf2f(v.w);
    }
    float r = 0.f;
    r += (dv.x > 0.f) ? num0 / dv.x : 0.f;
    r += (dv.y > 0.f) ? num1 / dv.y : 0.f;
    r += (dv.z > 0.f) ? num2 / dv.z : 0.f;
    r += (dv.w > 0.f) ? num3 / dv.w : 0.f;
    out[n * DD + lane] = 0.25f * r + bias[lane];
}

extern "C" void kernel_launch(void* const* d_in, const int* in_sizes, int n_in,
                              void* d_out, int out_size, void* d_ws, size_t ws_size,
                              hipStream_t stream)
{
    (void)in_sizes; (void)n_in; (void)out_size; (void)ws_size;
    const float* x    = (const float*)d_in[0];
    const float* ea   = (const float*)d_in[1];
    const float* W    = (const float*)d_in[2];
    const float* att  = (const float*)d_in[3];
    const float* bias = (const float*)d_in[4];
    const float* bn_g = (const float*)d_in[5];
    const float* bn_b = (const float*)d_in[6];
    const float* bn_m = (const float*)d_in[7];
    const float* bn_v = (const float*)d_in[8];
    const int*   eidx = (const int*)d_in[9];
    float* out = (float*)d_out;

    // ws layout: outj bf16 [E][64][4] (128 MB) | expa f32 [E][4] (4 MB) |
    //   denom f32 [N][4] | cnt [N] | offs [N+1] | cursor [N] | perm [E] |
    //   bsum/bbase | xw f32 [N][256] (25.6 MB)
    char* ws = (char*)d_ws;
    unsigned short* outj = (unsigned short*)ws;
    float* expa  = (float*)(ws + (size_t)NE * 512);
    float* denom = (float*)(ws + (size_t)NE * 512 + (size_t)NE * 16);
    int*   cnt    = (int*)(denom + (size_t)NN * 4);
    int*   offs   = cnt + NN;
    int*   cursor = offs + NN + 1;
    int*   perm   = cursor + NN;
    int*   bsum   = perm + NE;
    int*   bbase  = bsum + NB;
    float* xwbuf  = (float*)(bbase + NB + 2);

    // one memset covers denom (NN*4 floats) + cnt (NN ints), adjacent
    hipMemsetAsync(denom, 0, (size_t)NN * 5 * sizeof(int), stream);

    k_xw   <<<dim3((NGX + 7) / 8), dim3(512), 0, stream>>>(x, W, xwbuf);
    k_hist <<<dim3((NE + 255) / 256), dim3(256), 0, stream>>>(eidx, cnt);
    k_scanA<<<dim3(NB), dim3(256), 0, stream>>>(cnt, offs, bsum);
    k_scanB<<<dim3(1), dim3(128), 0, stream>>>(bsum, bbase);
    k_scanC<<<dim3(NB), dim3(256), 0, stream>>>(offs, bbase, cursor);
    k_place<<<dim3((NE + 255) / 256), dim3(256), 0, stream>>>(eidx, cursor, perm);

    k_edge<<<dim3(512), dim3(512), 0, stream>>>(
        ea, W, att, bn_g, bn_b, bn_m, bn_v, eidx, perm, xwbuf, outj, expa, denom);

    k_aggr<<<dim3((NN + 3) / 4), dim3(256), 0, stream>>>(
        offs, outj, expa, denom, bias, out);
}